// Round 13
// baseline (1926.171 us; speedup 1.0000x reference)
//
#include <hip/hip_runtime.h>
#include <math.h>

#define B_ 64
#define T_ 2048
#define E_ 128
#define H_ 128
#define G3_ 384   // 3*H
#define C_ 32
#define M_ (T_ * B_)   // 131072 tokens
#define CH_ 16         // pipeline chunk (steps)
#define NCH_ (T_ / CH_)

typedef _Float16 f16x2 __attribute__((ext_vector_type(2)));

__device__ __forceinline__ f16x2 as_h2(unsigned int u) {
    union { unsigned int u; f16x2 h; } c; c.u = u; return c.h;
}

#if __has_builtin(__builtin_amdgcn_fdot2)
__device__ __forceinline__ float fdot2_acc(f16x2 a, f16x2 b, float c) {
    return __builtin_amdgcn_fdot2(a, b, c, false);
}
#else
__device__ __forceinline__ float fdot2_acc(f16x2 a, f16x2 b, float c) {
    return fmaf((float)a.y, (float)b.y, fmaf((float)a.x, (float)b.x, c));
}
#endif

__device__ __forceinline__ void wait_ge(int* f, int need) {
    while (__hip_atomic_load(f, __ATOMIC_ACQUIRE, __HIP_MEMORY_SCOPE_AGENT) < need)
        __builtin_amdgcn_s_sleep(8);
}

// ---------------------------------------------------------------------------
// 4-stage cross-block GRU pipeline, round 13: QUAD-SPLIT K (uniform DOT48).
// 256 blocks x 512 threads (8 waves = 2/SIMD -> intra-CU TLP for the
// recurrence). Each h-dim owned by a 4-lane quad: lane holds 3 gate rows x
// K/4 = 48 weight f16x2 VGPRs (was 96) and issues 48 dot2 (96-cyc chain,
// was 192); reduce = shfl_xor(1) + shfl_xor(2). Kernel VGPR need ~90 ->
// immune to the 84-reg clamp that spilled the 768-thread fusion.
// Roles (blockIdx.x>>6), b = blockIdx.x&63:
//   0 GI0:  gi0[t,b] = b_ih0 + W_ih0 . emb[x[b,t]] per chunk; release q0.
//   1 L0:   recurrence gi0/w_hh0 -> y0; wait q0>=c+2; release p0=(c+1)*CH.
//   2 GEMM: gi1[t,b] = b_ih1 + W_ih1 . y0[t,b] IN-PLACE over consumed gi0;
//           wait p0; release p1.
//   3 L1:   recurrence gi1/w_hh1 -> y1 over ybuf; wait p1>=c+2.
// Flags q0|p0|p1 in d_out (memset'd; fc_relu overwrites d_out after).
// AGENT-scope release/acquire; monotone flags; 256 blocks = 1/CU co-resident.
// In-place/overwrite ordering proven in r11/r12.
// ---------------------------------------------------------------------------
#define DOT48(HSRC, S0, S1, S2)                                                \
  {                                                                            \
    float a00 = 0.f, a01 = 0.f, a10 = 0.f, a11 = 0.f, a20 = 0.f, a21 = 0.f;    \
    _Pragma("unroll")                                                          \
    for (int i = 0; i < 4; i++) {                                              \
      uint4 u = (HSRC)[i];                                                     \
      f16x2 ux = as_h2(u.x), uy = as_h2(u.y), uz = as_h2(u.z), uw = as_h2(u.w);\
      a00 = fdot2_acc(wr[0][4*i+0], ux, a00);                                  \
      a10 = fdot2_acc(wr[1][4*i+0], ux, a10);                                  \
      a20 = fdot2_acc(wr[2][4*i+0], ux, a20);                                  \
      a01 = fdot2_acc(wr[0][4*i+1], uy, a01);                                  \
      a11 = fdot2_acc(wr[1][4*i+1], uy, a11);                                  \
      a21 = fdot2_acc(wr[2][4*i+1], uy, a21);                                  \
      a00 = fdot2_acc(wr[0][4*i+2], uz, a00);                                  \
      a10 = fdot2_acc(wr[1][4*i+2], uz, a10);                                  \
      a20 = fdot2_acc(wr[2][4*i+2], uz, a20);                                  \
      a01 = fdot2_acc(wr[0][4*i+3], uw, a01);                                  \
      a11 = fdot2_acc(wr[1][4*i+3], uw, a11);                                  \
      a21 = fdot2_acc(wr[2][4*i+3], uw, a21);                                  \
    }                                                                          \
    S0 = a00 + a01; S1 = a10 + a11; S2 = a20 + a21;                            \
  }

#define RED4(S) { S += __shfl_xor(S, 1); S += __shfl_xor(S, 2); }

#define GSTEPQ(CUR, NXT, IR, IZ, INN, TT, TP)                                  \
  {                                                                            \
    const uint4* hsrc = (const uint4*)((const char*)hb[CUR] + kq * 64);        \
    float s0, s1, s2;                                                          \
    DOT48(hsrc, s0, s1, s2);                                                   \
    RED4(s0) RED4(s1) RED4(s2)                                                 \
    const float hr = s0 + bg0;                                                 \
    const float hz = s1 + bg1;                                                 \
    const float hn = s2 + bg2;                                                 \
    const float rr = 1.f / (1.f + __expf(-((IR) + hr)));                       \
    const float zz = 1.f / (1.f + __expf(-((IZ) + hz)));                       \
    const float na = (INN) + rr * hn;                                          \
    const float nn = 1.f - 2.f / (__expf(2.f * na) + 1.f);                     \
    h_own = (1.f - zz) * nn + zz * h_own;                                      \
    if (kq == 0) hb[NXT][g] = (_Float16)h_own;                                 \
    else if (kq == 1) y_g[(size_t)(TT) * (B_ * H_)] = h_own;                   \
    {                                                                          \
      const int tp = ((TP) < T_) ? (TP) : (TT);                                \
      const float* gp = gi_g + (size_t)tp * (B_ * G3_);                        \
      IR = gp[0]; IZ = gp[128]; INN = gp[256];                                 \
    }                                                                          \
    asm volatile("s_waitcnt lgkmcnt(0)" ::: "memory");                         \
    __builtin_amdgcn_s_barrier();                                              \
    __builtin_amdgcn_sched_barrier(0);                                         \
  }

__global__ __launch_bounds__(512, 1) void gru_pipe(
    const float* __restrict__ emb,    // [V,128]
    const int*   __restrict__ xidx,   // [B,T]
    const float* __restrict__ w_ih0,  // [384,128]
    const float* __restrict__ b_ih0,  // [384]
    float* __restrict__ gi,           // [M,384] gi0, overwritten in-place by gi1
    const float* __restrict__ w_hh0,  // [384,128]
    const float* __restrict__ b_hh0,  // [384]
    const float* __restrict__ w_ih1,  // [384,128]
    const float* __restrict__ b_ih1,  // [384]
    const float* __restrict__ w_hh1,  // [384,128]
    const float* __restrict__ b_hh1,  // [384]
    float* __restrict__ ybuf,         // [M,128] y0 then y1 (flag-ordered)
    int* __restrict__ flags)          // q0[64] | p0[64] | p1[64]  (in d_out)
{
    const int tid = threadIdx.x;
    const int w   = tid >> 6;        // wave 0..7
    const int l   = tid & 63;
    const int g   = w * 16 + (l >> 2);   // owned dim (quad-shared)
    const int kq  = l & 3;               // K-quarter
    const int role = blockIdx.x >> 6;    // 0=GI0, 1=L0, 2=GEMM, 3=L1
    const int b    = blockIdx.x & 63;
    int* q0 = flags + b;
    int* p0 = flags + 64 + b;
    int* p1 = flags + 128 + b;

    __shared__ __align__(16) _Float16 hb[2][128];   // recurrence h dbuf
    __shared__ __align__(16) f16x2 srow[16][64];    // GEMM stages: 16 rows f16

    if (role == 0 || role == 2) {
        // ------- GEMM-type stage: out_rows = bias + W . staged_rows --------
        const float* wsrc = (role == 0) ? w_ih0 : w_ih1;
        const float* bsrc = (role == 0) ? b_ih0 : b_ih1;
        f16x2 wr[3][16];
#pragma unroll
        for (int G = 0; G < 3; G++) {
            const float2* w2 = (const float2*)(wsrc + (size_t)(g + 128 * G) * 128 + kq * 32);
#pragma unroll
            for (int i = 0; i < 16; i++) {
                float2 v = w2[i];
                wr[G][i] = (f16x2){(_Float16)v.x, (_Float16)v.y};
            }
        }
        const float c0 = bsrc[g], c1 = bsrc[g + 128], c2 = bsrc[g + 256];

        for (int c = 0; c < NCH_; c++) {
            if (role == 2) {
                if (tid == 0) wait_ge(p0, (c + 1) * CH_);
            }
            __syncthreads();   // chunk-ready visible; protects srow reuse
            // stage 16 input rows as f16: GI0 = emb[x[b,t]]; GEMM = y0[t,b]
            for (int j = tid; j < 16 * 64; j += 512) {
                const int s = j >> 6, p = j & 63;
                const float* src;
                if (role == 0) {
                    const long row = (long)xidx[b * T_ + c * CH_ + s];
                    src = emb + row * 128;
                } else {
                    src = ybuf + ((size_t)(c * CH_ + s) * B_ + b) * H_;
                }
                const float2 v = ((const float2*)src)[p];
                srow[s][p] = (f16x2){(_Float16)v.x, (_Float16)v.y};
            }
            __syncthreads();
            for (int s = 0; s < 16; s++) {
                const uint4* hsrc = (const uint4*)srow[s] + kq * 4;
                float s0, s1, s2;
                DOT48(hsrc, s0, s1, s2);
                RED4(s0) RED4(s1) RED4(s2)
                if (kq == 0) {
                    float* go = gi + ((size_t)(c * CH_ + s) * B_ + b) * G3_ + g;
                    go[0]   = s0 + c0;
                    go[128] = s1 + c1;
                    go[256] = s2 + c2;
                }
            }
            asm volatile("s_waitcnt vmcnt(0)" ::: "memory");  // gi stores done
            __syncthreads();
            if (tid == 0) {
                int* rel = (role == 0) ? q0 : p1;
                __hip_atomic_store(rel, c + 1, __ATOMIC_RELEASE, __HIP_MEMORY_SCOPE_AGENT);
            }
        }
        return;
    }

    // ------------------- recurrence (role 1 = L0, role 3 = L1) ------------
    const float* wsrc = (role == 3) ? w_hh1 : w_hh0;
    const float* bsrc = (role == 3) ? b_hh1 : b_hh0;
    int* wf = (role == 3) ? p1 : q0;     // upstream chunk flag

    f16x2 wr[3][16];
#pragma unroll
    for (int G = 0; G < 3; G++) {
        const float2* w2 = (const float2*)(wsrc + (size_t)(g + 128 * G) * 128 + kq * 32);
#pragma unroll
        for (int i = 0; i < 16; i++) {
            float2 v = w2[i];
            wr[G][i] = (f16x2){(_Float16)v.x, (_Float16)v.y};
        }
    }
    const float bg0 = bsrc[g];
    const float bg1 = bsrc[g + 128];
    const float bg2 = bsrc[g + 256];

    if (tid < 128) hb[0][tid] = (_Float16)0.f;
    float h_own = 0.f;

    const float* gi_g = gi + (size_t)b * G3_ + g;
    float* y_g = ybuf + (size_t)b * H_ + g;

    // prologue prefetch (rows 0,1) requires upstream chunks 0,1 ready
    if (tid == 0) wait_ge(wf, 2);
    __syncthreads();

    float irA = gi_g[0], izA = gi_g[128], innA = gi_g[256];
    const float* pp1 = gi_g + (size_t)(B_ * G3_);
    float irB = pp1[0], izB = pp1[128], innB = pp1[256];

    __syncthreads();  // hb[0] init visible

    for (int c = 0; c < NCH_; c++) {
        const int need = (c + 2 < NCH_) ? (c + 2) : NCH_;
        if (tid == 0) wait_ge(wf, need);
        __syncthreads();
        const int t0 = c * CH_;
        for (int i = 0; i < CH_ / 2; i++) {
            const int t = t0 + 2 * i;
            GSTEPQ(0, 1, irA, izA, innA, t,     t + 2)
            GSTEPQ(1, 0, irB, izB, innB, t + 1, t + 3)
        }
        if (role == 1) {
            asm volatile("s_waitcnt vmcnt(0)" ::: "memory");  // y0 stores done
            __syncthreads();
            if (tid == 0)
                __hip_atomic_store(p0, (c + 1) * CH_, __ATOMIC_RELEASE, __HIP_MEMORY_SCOPE_AGENT);
        }
    }
}

// ---------------------------------------------------------------------------
// K5: out[b*T+t][c] = relu(fc_b[c] + dot(fc_w[c], y[t*B+b]))
// ---------------------------------------------------------------------------
__global__ __launch_bounds__(256, 2) void fc_relu(
    const float* __restrict__ y,     // [M,128]
    const float* __restrict__ fc_w,  // [32,128]
    const float* __restrict__ fc_b,  // [32]
    float* __restrict__ out)         // [B*T,32]
{
    const int tid = threadIdx.x;
    const int c = tid & 31;
    const int slot = tid >> 5;

    float4 wr[32];
    const float4* w4 = (const float4*)(fc_w + c * 128);
#pragma unroll
    for (int i = 0; i < 32; i++) wr[i] = w4[i];
    const float bc = fc_b[c];

    __shared__ __align__(16) float rows[8][128];

    for (int grp = blockIdx.x; grp < M_ / 8; grp += gridDim.x) {
        const int m0 = grp * 8;
        __syncthreads();
        for (int i = tid; i < 8 * 128; i += 256) {
            rows[i >> 7][i & 127] = y[(long)m0 * 128 + i];
        }
        __syncthreads();
        const float4* h4 = (const float4*)rows[slot];
        float a0 = bc, a1 = 0.f, a2 = 0.f, a3 = 0.f;
#pragma unroll
        for (int i = 0; i < 32; i += 4) {
            float4 h0 = h4[i], h1 = h4[i + 1], h2 = h4[i + 2], h3 = h4[i + 3];
            a0 = fmaf(wr[i].w, h0.w, fmaf(wr[i].z, h0.z, fmaf(wr[i].y, h0.y, fmaf(wr[i].x, h0.x, a0))));
            a1 = fmaf(wr[i+1].w, h1.w, fmaf(wr[i+1].z, h1.z, fmaf(wr[i+1].y, h1.y, fmaf(wr[i+1].x, h1.x, a1))));
            a2 = fmaf(wr[i+2].w, h2.w, fmaf(wr[i+2].z, h2.z, fmaf(wr[i+2].y, h2.y, fmaf(wr[i+2].x, h2.x, a2))));
            a3 = fmaf(wr[i+3].w, h3.w, fmaf(wr[i+3].z, h3.z, fmaf(wr[i+3].y, h3.y, fmaf(wr[i+3].x, h3.x, a3))));
        }
        float acc = (a0 + a1) + (a2 + a3);
        acc = fmaxf(acc, 0.f);
        const int m = m0 + slot;
        const int t = m >> 6;
        const int b = m & 63;
        out[((long)b * T_ + t) * C_ + c] = acc;
    }
}

// ---------------------------------------------------------------------------
extern "C" void kernel_launch(void* const* d_in, const int* in_sizes, int n_in,
                              void* d_out, int out_size, void* d_ws, size_t ws_size,
                              hipStream_t stream) {
    const int*   x     = (const int*)d_in[0];
    const float* emb   = (const float*)d_in[1];
    const float* w_ih0 = (const float*)d_in[2];
    const float* w_hh0 = (const float*)d_in[3];
    const float* b_ih0 = (const float*)d_in[4];
    const float* b_hh0 = (const float*)d_in[5];
    const float* w_ih1 = (const float*)d_in[6];
    const float* w_hh1 = (const float*)d_in[7];
    const float* b_ih1 = (const float*)d_in[8];
    const float* b_hh1 = (const float*)d_in[9];
    const float* fc_w  = (const float*)d_in[10];
    const float* fc_b  = (const float*)d_in[11];
    float* out = (float*)d_out;

    // workspace: gi [M,384] fp32 (201.3 MB, gi0 overwritten in-place by gi1)
    //          + ybuf [M,128] fp32 (67.1 MB, y0 then y1) = 268.4 MB
    float* gi   = (float*)d_ws;
    float* ybuf = (float*)((char*)d_ws + (size_t)M_ * G3_ * sizeof(float));

    // pipeline flags q0|p0|p1 at the start of d_out (overwritten by fc_relu)
    hipMemsetAsync(d_out, 0, 192 * sizeof(int), stream);

    // 4-stage pipelined model: GI0 | L0 | gi1-GEMM | L1
    gru_pipe<<<256, 512, 0, stream>>>(emb, x, w_ih0, b_ih0, gi,
                                      w_hh0, b_hh0, w_ih1, b_ih1, w_hh1, b_hh1,
                                      ybuf, (int*)d_out);
    // FC + ReLU
    fc_relu<<<512, 256, 0, stream>>>(ybuf, fc_w, fc_b, out);
}

// Round 15
// 1524.443 us; speedup vs baseline: 1.2635x; 1.2635x over previous
//
#include <hip/hip_runtime.h>
#include <math.h>

#define B_ 64
#define T_ 2048
#define E_ 128
#define H_ 128
#define G3_ 384   // 3*H
#define C_ 32
#define M_ (T_ * B_)   // 131072 tokens
#define CH_ 16         // pipeline chunk (steps)
#define NCH_ (T_ / CH_)

typedef _Float16 f16x2 __attribute__((ext_vector_type(2)));
typedef _Float16 f16x8 __attribute__((ext_vector_type(8)));
typedef float f32x4 __attribute__((ext_vector_type(4)));

__device__ __forceinline__ f16x2 as_h2(unsigned int u) {
    union { unsigned int u; f16x2 h; } c; c.u = u; return c.h;
}

#if __has_builtin(__builtin_amdgcn_fdot2)
__device__ __forceinline__ float fdot2_acc(f16x2 a, f16x2 b, float c) {
    return __builtin_amdgcn_fdot2(a, b, c, false);
}
#else
__device__ __forceinline__ float fdot2_acc(f16x2 a, f16x2 b, float c) {
    return fmaf((float)a.y, (float)b.y, fmaf((float)a.x, (float)b.x, c));
}
#endif

__device__ __forceinline__ void wait_ge(int* f, int need) {
    while (__hip_atomic_load(f, __ATOMIC_ACQUIRE, __HIP_MEMORY_SCOPE_AGENT) < need)
        __builtin_amdgcn_s_sleep(8);
}

// ---------------------------------------------------------------------------
// K1 (round 14): MFMA gates GEMM. gi0[m][r] = b_ih0[r] + W_ih0[r,:].emb[x].
// The dot2 version was VALU-issue-bound (~210 us serial); this is a
// 12.9-GFLOP GEMM -> MFMA puts it at the memory floor (~45-60 us).
// Fragment maps identical to the r5-verified usage of mfma_f32_16x16x32_f16:
// A = W rows (lane: row=l&15, k=ks*32+(l>>4)*8+j), B = token cols (col=l&15,
// same k), D: col=l&15 (token), row=4*(l>>4)+reg (out).
// Grid 1536 = 3 out-blocks x 512 token-stripes; 256 thr (4 waves); wave q
// owns out rows [ob*128+q*32, +32) as 8 stationary A-frags (64 VGPRs).
// 16 tokens staged per group in XOR-swizzled LDS (2-way conflicts only).
// ---------------------------------------------------------------------------
__global__ __launch_bounds__(256, 1) void gates_mfma(
    const float* __restrict__ emb,   // [V,128]
    const int*   __restrict__ xidx,  // [B,T]
    const float* __restrict__ w,     // [384,128]
    const float* __restrict__ bias,  // [384]
    float* __restrict__ gi)          // [M,384]
{
    const int tid = threadIdx.x;
    const int q   = tid >> 6;        // wave 0..3
    const int l   = tid & 63;
    const int rl  = l & 15;          // A row / B col / D col within tile
    const int kg  = l >> 4;          // 0..3
    const int ob  = blockIdx.x % 3;          // out-block (128 outs)
    const int stripe = blockIdx.x / 3;       // 0..511
    const int obase  = ob * 128 + q * 32;    // this wave's first out row

    // stationary A-frags: W[obase + p*16 + rl][ks*32 + kg*8 + 0..7]
    f16x8 aF[2][4];
#pragma unroll
    for (int p = 0; p < 2; p++) {
        const float* wrow = w + (size_t)(obase + p * 16 + rl) * 128 + kg * 8;
#pragma unroll
        for (int ks = 0; ks < 4; ks++) {
            const f32x4 lo = *(const f32x4*)(wrow + ks * 32);
            const f32x4 hi = *(const f32x4*)(wrow + ks * 32 + 4);
            aF[p][ks] = (f16x8){(_Float16)lo[0], (_Float16)lo[1], (_Float16)lo[2], (_Float16)lo[3],
                                (_Float16)hi[0], (_Float16)hi[1], (_Float16)hi[2], (_Float16)hi[3]};
        }
    }
    // bias pre-load into accumulator-init vectors: out = obase + p*16 + 4*kg + r
    f32x4 bv[2];
#pragma unroll
    for (int p = 0; p < 2; p++)
#pragma unroll
        for (int r = 0; r < 4; r++)
            bv[p][r] = bias[obase + p * 16 + 4 * kg + r];

    // 16 tokens x 128 f16 (256 B/row), XOR-swizzled by ((tok&7)<<4)
    __shared__ __align__(16) char rows[4096];

    for (int g = stripe; g < M_ / 16; g += 512) {
        const int m0 = g * 16;
        __syncthreads();  // protect rows[] from previous group's readers
        // stage 16 token rows (f16): 1024 f16x2 slots, 4 per thread
#pragma unroll
        for (int k = 0; k < 4; k++) {
            const int j = tid + 256 * k;
            const int s = j >> 6;            // token in group
            const int p2 = j & 63;           // f16x2 slot within row
            const int mm = m0 + s;
            const int t = mm >> 6;           // m = t*B + b
            const int bb = mm & 63;
            const long row = (long)xidx[bb * T_ + t];
            const float2 v = ((const float2*)(emb + row * 128))[p2];
            const int byte = (s * 256 + p2 * 4) ^ ((s & 7) << 4);
            *(f16x2*)(rows + byte) = (f16x2){(_Float16)v.x, (_Float16)v.y};
        }
        __syncthreads();
        f32x4 acc0 = bv[0], acc1 = bv[1];
#pragma unroll
        for (int ks = 0; ks < 4; ks++) {
            const int byte = (rl * 256 + ks * 64 + kg * 16) ^ ((rl & 7) << 4);
            const f16x8 bf = *(const f16x8*)(rows + byte);
            acc0 = __builtin_amdgcn_mfma_f32_16x16x32_f16(aF[0][ks], bf, acc0, 0, 0, 0);
            acc1 = __builtin_amdgcn_mfma_f32_16x16x32_f16(aF[1][ks], bf, acc1, 0, 0, 0);
        }
        // store: token m0+rl, outs obase + p*16 + 4*kg + 0..3 (16B aligned)
        float* go = gi + (size_t)(m0 + rl) * G3_ + obase + 4 * kg;
        *(f32x4*)(go)      = acc0;
        *(f32x4*)(go + 16) = acc1;
    }
}

// ---------------------------------------------------------------------------
// K2: 3-stage cross-block GRU pipeline (r11 verbatim — best measured config;
// r12's GI0-absorption and r13's quad-split both regressed the recurrence).
// 192 blocks x 256 threads: [0,64) L0 | [64,128) gi1-GEMM | [128,192) L1.
// Pair-split dot (96 weight VGPRs, 96 dot2), shfl_xor(1) combine, one raw
// s_barrier/step, gi prefetched 2 steps ahead, AGENT-scope flag handshake.
// ---------------------------------------------------------------------------
#define DOT96(HSRC, S0, S1, S2)                                                \
  {                                                                            \
    float a00 = 0.f, a01 = 0.f, a10 = 0.f, a11 = 0.f, a20 = 0.f, a21 = 0.f;    \
    _Pragma("unroll")                                                          \
    for (int i = 0; i < 8; i++) {                                              \
      uint4 u = (HSRC)[i];                                                     \
      f16x2 ux = as_h2(u.x), uy = as_h2(u.y), uz = as_h2(u.z), uw = as_h2(u.w);\
      a00 = fdot2_acc(wr[0][4*i+0], ux, a00);                                  \
      a10 = fdot2_acc(wr[1][4*i+0], ux, a10);                                  \
      a20 = fdot2_acc(wr[2][4*i+0], ux, a20);                                  \
      a01 = fdot2_acc(wr[0][4*i+1], uy, a01);                                  \
      a11 = fdot2_acc(wr[1][4*i+1], uy, a11);                                  \
      a21 = fdot2_acc(wr[2][4*i+1], uy, a21);                                  \
      a00 = fdot2_acc(wr[0][4*i+2], uz, a00);                                  \
      a10 = fdot2_acc(wr[1][4*i+2], uz, a10);                                  \
      a20 = fdot2_acc(wr[2][4*i+2], uz, a20);                                  \
      a01 = fdot2_acc(wr[0][4*i+3], uw, a01);                                  \
      a11 = fdot2_acc(wr[1][4*i+3], uw, a11);                                  \
      a21 = fdot2_acc(wr[2][4*i+3], uw, a21);                                  \
    }                                                                          \
    S0 = a00 + a01; S1 = a10 + a11; S2 = a20 + a21;                            \
  }

#define GSTEPX(CUR, NXT, IR, IZ, INN, TT, TP)                                  \
  {                                                                            \
    const uint4* hsrc = (const uint4*)((const char*)hb[CUR] + kh * 128);       \
    float s0, s1, s2;                                                          \
    DOT96(hsrc, s0, s1, s2);                                                   \
    const float hr = s0 + __shfl_xor(s0, 1) + bg0;                             \
    const float hz = s1 + __shfl_xor(s1, 1) + bg1;                             \
    const float hn = s2 + __shfl_xor(s2, 1) + bg2;                             \
    const float rr = 1.f / (1.f + __expf(-((IR) + hr)));                       \
    const float zz = 1.f / (1.f + __expf(-((IZ) + hz)));                       \
    const float na = (INN) + rr * hn;                                          \
    const float nn = 1.f - 2.f / (__expf(2.f * na) + 1.f);                     \
    h_own = (1.f - zz) * nn + zz * h_own;                                      \
    if (kh == 0) hb[NXT][g] = (_Float16)h_own;                                 \
    else         y_g[(size_t)(TT) * (B_ * H_)] = h_own;                        \
    {                                                                          \
      const int tp = ((TP) < T_) ? (TP) : (TT);                                \
      const float* gp = gi_g + (size_t)tp * (B_ * G3_);                        \
      IR = gp[0]; IZ = gp[128]; INN = gp[256];                                 \
    }                                                                          \
    asm volatile("s_waitcnt lgkmcnt(0)" ::: "memory");                         \
    __builtin_amdgcn_s_barrier();                                              \
    __builtin_amdgcn_sched_barrier(0);                                         \
  }

__global__ __launch_bounds__(256, 1) void gru_pipe(
    float* __restrict__ gi,           // [M,384] gi0, overwritten in-place by gi1
    const float* __restrict__ w_hh0,  // [384,128]
    const float* __restrict__ b_hh0,  // [384]
    const float* __restrict__ w_ih1,  // [384,128]
    const float* __restrict__ b_ih1,  // [384]
    const float* __restrict__ w_hh1,  // [384,128]
    const float* __restrict__ b_hh1,  // [384]
    float* __restrict__ ybuf,         // [M,128] y0 then y1 (flag-ordered)
    int* __restrict__ flags)          // p0[64] | p1[64]  (in d_out)
{
    const int tid = threadIdx.x;
    const int w   = tid >> 6;        // wave 0..3
    const int l   = tid & 63;
    const int g   = w * 32 + (l >> 1);   // owned dim (pair-shared)
    const int kh  = l & 1;               // K-half
    const int role = blockIdx.x >> 6;    // 0=L0, 1=GEMM, 2=L1
    const int b    = blockIdx.x & 63;
    int* p0 = flags + b;
    int* p1 = flags + 64 + b;

    __shared__ __align__(16) _Float16 hb[2][128];   // recurrence h dbuf
    __shared__ __align__(16) f16x2 yrow[16][64];    // GEMM: 16 staged y0 rows

    if (role == 1) {
        // ------------------- GEMM stage: gi1 = b_ih1 + W_ih1 . y0 ---------
        f16x2 wr[3][32];
#pragma unroll
        for (int G = 0; G < 3; G++) {
            const float2* w2 = (const float2*)(w_ih1 + (size_t)(g + 128 * G) * 128 + kh * 64);
#pragma unroll
            for (int i = 0; i < 32; i++) {
                float2 v = w2[i];
                wr[G][i] = (f16x2){(_Float16)v.x, (_Float16)v.y};
            }
        }
        const float c0 = b_ih1[g], c1 = b_ih1[g + 128], c2 = b_ih1[g + 256];

        for (int c = 0; c < NCH_; c++) {
            if (tid == 0) wait_ge(p0, (c + 1) * CH_);
            __syncthreads();   // all threads see chunk-ready; also protects yrow
            for (int j = tid; j < 16 * 64; j += 256) {
                const int s = j >> 6, p = j & 63;
                const float2 v = ((const float2*)(ybuf +
                    ((size_t)(c * CH_ + s) * B_ + b) * H_))[p];
                yrow[s][p] = (f16x2){(_Float16)v.x, (_Float16)v.y};
            }
            __syncthreads();
            for (int s = 0; s < 16; s++) {
                const uint4* hsrc = (const uint4*)yrow[s] + kh * 8;
                float s0, s1, s2;
                DOT96(hsrc, s0, s1, s2);
                const float r0v = s0 + __shfl_xor(s0, 1);
                const float r1v = s1 + __shfl_xor(s1, 1);
                const float r2v = s2 + __shfl_xor(s2, 1);
                if (kh == 0) {
                    float* go = gi + ((size_t)(c * CH_ + s) * B_ + b) * G3_ + g;
                    go[0]   = r0v + c0;
                    go[128] = r1v + c1;
                    go[256] = r2v + c2;
                }
            }
            asm volatile("s_waitcnt vmcnt(0)" ::: "memory");  // gi1 stores done
            __syncthreads();
            if (tid == 0)
                __hip_atomic_store(p1, c + 1, __ATOMIC_RELEASE, __HIP_MEMORY_SCOPE_AGENT);
        }
        return;
    }

    // ------------------- recurrence (role 0 = L0, role 2 = L1) ------------
    const float* wsrc = (role == 2) ? w_hh1 : w_hh0;
    const float* bsrc = (role == 2) ? b_hh1 : b_hh0;

    f16x2 wr[3][32];
#pragma unroll
    for (int G = 0; G < 3; G++) {
        const float2* w2 = (const float2*)(wsrc + (size_t)(g + 128 * G) * 128 + kh * 64);
#pragma unroll
        for (int i = 0; i < 32; i++) {
            float2 v = w2[i];
            wr[G][i] = (f16x2){(_Float16)v.x, (_Float16)v.y};
        }
    }
    const float bg0 = bsrc[g];
    const float bg1 = bsrc[g + 128];
    const float bg2 = bsrc[g + 256];

    if (tid < 128) hb[0][tid] = (_Float16)0.f;
    float h_own = 0.f;

    const float* gi_g = gi + (size_t)b * G3_ + g;
    float* y_g = ybuf + (size_t)b * H_ + g;

    // L1: gate prologue prefetch (rows 0,1) requires gi1 chunks 0,1 ready
    if (role == 2) {
        if (tid == 0) wait_ge(p1, 2);
        __syncthreads();
    }

    float irA = gi_g[0], izA = gi_g[128], innA = gi_g[256];
    const float* pp1 = gi_g + (size_t)(B_ * G3_);
    float irB = pp1[0], izB = pp1[128], innB = pp1[256];

    __syncthreads();  // hb[0] init visible

    for (int c = 0; c < NCH_; c++) {
        if (role == 2) {
            const int need = (c + 2 < NCH_) ? (c + 2) : NCH_;
            if (tid == 0) wait_ge(p1, need);
            __syncthreads();
        }
        const int t0 = c * CH_;
        for (int i = 0; i < CH_ / 2; i++) {
            const int t = t0 + 2 * i;
            GSTEPX(0, 1, irA, izA, innA, t,     t + 2)
            GSTEPX(1, 0, irB, izB, innB, t + 1, t + 3)
        }
        if (role == 0) {
            asm volatile("s_waitcnt vmcnt(0)" ::: "memory");  // y0 stores done
            __syncthreads();
            if (tid == 0)
                __hip_atomic_store(p0, (c + 1) * CH_, __ATOMIC_RELEASE, __HIP_MEMORY_SCOPE_AGENT);
        }
    }
}

// ---------------------------------------------------------------------------
// K5: out[b*T+t][c] = relu(fc_b[c] + dot(fc_w[c], y[t*B+b]))
// ---------------------------------------------------------------------------
__global__ __launch_bounds__(256, 2) void fc_relu(
    const float* __restrict__ y,     // [M,128]
    const float* __restrict__ fc_w,  // [32,128]
    const float* __restrict__ fc_b,  // [32]
    float* __restrict__ out)         // [B*T,32]
{
    const int tid = threadIdx.x;
    const int c = tid & 31;
    const int slot = tid >> 5;

    float4 wr[32];
    const float4* w4 = (const float4*)(fc_w + c * 128);
#pragma unroll
    for (int i = 0; i < 32; i++) wr[i] = w4[i];
    const float bc = fc_b[c];

    __shared__ __align__(16) float rows[8][128];

    for (int grp = blockIdx.x; grp < M_ / 8; grp += gridDim.x) {
        const int m0 = grp * 8;
        __syncthreads();
        for (int i = tid; i < 8 * 128; i += 256) {
            rows[i >> 7][i & 127] = y[(long)m0 * 128 + i];
        }
        __syncthreads();
        const float4* h4 = (const float4*)rows[slot];
        float a0 = bc, a1 = 0.f, a2 = 0.f, a3 = 0.f;
#pragma unroll
        for (int i = 0; i < 32; i += 4) {
            float4 h0 = h4[i], h1 = h4[i + 1], h2 = h4[i + 2], h3 = h4[i + 3];
            a0 = fmaf(wr[i].w, h0.w, fmaf(wr[i].z, h0.z, fmaf(wr[i].y, h0.y, fmaf(wr[i].x, h0.x, a0))));
            a1 = fmaf(wr[i+1].w, h1.w, fmaf(wr[i+1].z, h1.z, fmaf(wr[i+1].y, h1.y, fmaf(wr[i+1].x, h1.x, a1))));
            a2 = fmaf(wr[i+2].w, h2.w, fmaf(wr[i+2].z, h2.z, fmaf(wr[i+2].y, h2.y, fmaf(wr[i+2].x, h2.x, a2))));
            a3 = fmaf(wr[i+3].w, h3.w, fmaf(wr[i+3].z, h3.z, fmaf(wr[i+3].y, h3.y, fmaf(wr[i+3].x, h3.x, a3))));
        }
        float acc = (a0 + a1) + (a2 + a3);
        acc = fmaxf(acc, 0.f);
        const int m = m0 + slot;
        const int t = m >> 6;
        const int b = m & 63;
        out[((long)b * T_ + t) * C_ + c] = acc;
    }
}

// ---------------------------------------------------------------------------
extern "C" void kernel_launch(void* const* d_in, const int* in_sizes, int n_in,
                              void* d_out, int out_size, void* d_ws, size_t ws_size,
                              hipStream_t stream) {
    const int*   x     = (const int*)d_in[0];
    const float* emb   = (const float*)d_in[1];
    const float* w_ih0 = (const float*)d_in[2];
    const float* w_hh0 = (const float*)d_in[3];
    const float* b_ih0 = (const float*)d_in[4];
    const float* b_hh0 = (const float*)d_in[5];
    const float* w_ih1 = (const float*)d_in[6];
    const float* w_hh1 = (const float*)d_in[7];
    const float* b_ih1 = (const float*)d_in[8];
    const float* b_hh1 = (const float*)d_in[9];
    const float* fc_w  = (const float*)d_in[10];
    const float* fc_b  = (const float*)d_in[11];
    float* out = (float*)d_out;

    // workspace: gi [M,384] fp32 (201.3 MB, gi0 overwritten in-place by gi1)
    //          + ybuf [M,128] fp32 (67.1 MB, y0 then y1) = 268.4 MB
    float* gi   = (float*)d_ws;
    float* ybuf = (float*)((char*)d_ws + (size_t)M_ * G3_ * sizeof(float));

    // pipeline flags p0|p1 at the start of d_out (overwritten by fc_relu)
    hipMemsetAsync(d_out, 0, 128 * sizeof(int), stream);

    // layer 0 input gates: MFMA GEMM (was the 210-us dot2 prologue)
    gates_mfma<<<1536, 256, 0, stream>>>(emb, x, w_ih0, b_ih0, gi);
    // 3-stage pipelined recurrence: L0 | gi1-GEMM | L1 (r11 config)
    gru_pipe<<<192, 256, 0, stream>>>(gi, w_hh0, b_hh0, w_ih1, b_ih1, w_hh1, b_hh1,
                                      ybuf, (int*)d_out);
    // FC + ReLU
    fc_relu<<<512, 256, 0, stream>>>(ybuf, fc_w, fc_b, out);
}

// Round 16
// 1499.798 us; speedup vs baseline: 1.2843x; 1.0164x over previous
//
#include <hip/hip_runtime.h>
#include <math.h>

#define B_ 64
#define T_ 2048
#define E_ 128
#define H_ 128
#define G3_ 384   // 3*H
#define C_ 32
#define M_ (T_ * B_)   // 131072 tokens
#define CH_ 32         // pipeline chunk (steps) — r16: 16->32 halves handshakes
#define NCH_ (T_ / CH_)

typedef _Float16 f16x2 __attribute__((ext_vector_type(2)));
typedef _Float16 f16x8 __attribute__((ext_vector_type(8)));
typedef float f32x4 __attribute__((ext_vector_type(4)));

__device__ __forceinline__ f16x2 as_h2(unsigned int u) {
    union { unsigned int u; f16x2 h; } c; c.u = u; return c.h;
}

#if __has_builtin(__builtin_amdgcn_fdot2)
__device__ __forceinline__ float fdot2_acc(f16x2 a, f16x2 b, float c) {
    return __builtin_amdgcn_fdot2(a, b, c, false);
}
#else
__device__ __forceinline__ float fdot2_acc(f16x2 a, f16x2 b, float c) {
    return fmaf((float)a.y, (float)b.y, fmaf((float)a.x, (float)b.x, c));
}
#endif

__device__ __forceinline__ void wait_ge(int* f, int need) {
    while (__hip_atomic_load(f, __ATOMIC_ACQUIRE, __HIP_MEMORY_SCOPE_AGENT) < need)
        __builtin_amdgcn_s_sleep(8);
}

// ---------------------------------------------------------------------------
// K1: MFMA gates GEMM (r14, verified r15: ~60-100 us, replaced 210-us dot2).
// gi0[m][r] = b_ih0[r] + W_ih0[r,:].emb[x]. Fragment maps verified r5/r15.
// ---------------------------------------------------------------------------
__global__ __launch_bounds__(256, 1) void gates_mfma(
    const float* __restrict__ emb,   // [V,128]
    const int*   __restrict__ xidx,  // [B,T]
    const float* __restrict__ w,     // [384,128]
    const float* __restrict__ bias,  // [384]
    float* __restrict__ gi)          // [M,384]
{
    const int tid = threadIdx.x;
    const int q   = tid >> 6;        // wave 0..3
    const int l   = tid & 63;
    const int rl  = l & 15;          // A row / B col / D col within tile
    const int kg  = l >> 4;          // 0..3
    const int ob  = blockIdx.x % 3;          // out-block (128 outs)
    const int stripe = blockIdx.x / 3;       // 0..511
    const int obase  = ob * 128 + q * 32;    // this wave's first out row

    f16x8 aF[2][4];
#pragma unroll
    for (int p = 0; p < 2; p++) {
        const float* wrow = w + (size_t)(obase + p * 16 + rl) * 128 + kg * 8;
#pragma unroll
        for (int ks = 0; ks < 4; ks++) {
            const f32x4 lo = *(const f32x4*)(wrow + ks * 32);
            const f32x4 hi = *(const f32x4*)(wrow + ks * 32 + 4);
            aF[p][ks] = (f16x8){(_Float16)lo[0], (_Float16)lo[1], (_Float16)lo[2], (_Float16)lo[3],
                                (_Float16)hi[0], (_Float16)hi[1], (_Float16)hi[2], (_Float16)hi[3]};
        }
    }
    f32x4 bv[2];
#pragma unroll
    for (int p = 0; p < 2; p++)
#pragma unroll
        for (int r = 0; r < 4; r++)
            bv[p][r] = bias[obase + p * 16 + 4 * kg + r];

    __shared__ __align__(16) char rows[4096];

    for (int g = stripe; g < M_ / 16; g += 512) {
        const int m0 = g * 16;
        __syncthreads();
#pragma unroll
        for (int k = 0; k < 4; k++) {
            const int j = tid + 256 * k;
            const int s = j >> 6;
            const int p2 = j & 63;
            const int mm = m0 + s;
            const int t = mm >> 6;
            const int bb = mm & 63;
            const long row = (long)xidx[bb * T_ + t];
            const float2 v = ((const float2*)(emb + row * 128))[p2];
            const int byte = (s * 256 + p2 * 4) ^ ((s & 7) << 4);
            *(f16x2*)(rows + byte) = (f16x2){(_Float16)v.x, (_Float16)v.y};
        }
        __syncthreads();
        f32x4 acc0 = bv[0], acc1 = bv[1];
#pragma unroll
        for (int ks = 0; ks < 4; ks++) {
            const int byte = (rl * 256 + ks * 64 + kg * 16) ^ ((rl & 7) << 4);
            const f16x8 bf = *(const f16x8*)(rows + byte);
            acc0 = __builtin_amdgcn_mfma_f32_16x16x32_f16(aF[0][ks], bf, acc0, 0, 0, 0);
            acc1 = __builtin_amdgcn_mfma_f32_16x16x32_f16(aF[1][ks], bf, acc1, 0, 0, 0);
        }
        float* go = gi + (size_t)(m0 + rl) * G3_ + obase + 4 * kg;
        *(f32x4*)(go)      = acc0;
        *(f32x4*)(go + 16) = acc1;
    }
}

// ---------------------------------------------------------------------------
// K2: 3-stage cross-block GRU pipeline. r16 changes on the r11/r15 record:
//  (1) CH=32 (handshake count halved; +1 chunk fill).
//  (2) rolling gi-prefetch / y-store pointers (no per-step 64-bit mad chain,
//      no tail clamp: prefetch at t=2046/2047 reads <=98 KB past gi into
//      ybuf — in-bounds of ws, values never consumed).
//  (3) sched_barrier(0) -> sched_barrier(0x26): VALU|SALU|VMEM_READ may
//      cross the step barrier (addr math + gi loads overlap the barrier
//      wait); DS ops stay pinned (write->barrier->read ordering intact).
// ---------------------------------------------------------------------------
#define DOT96(HSRC, S0, S1, S2)                                                \
  {                                                                            \
    float a00 = 0.f, a01 = 0.f, a10 = 0.f, a11 = 0.f, a20 = 0.f, a21 = 0.f;    \
    _Pragma("unroll")                                                          \
    for (int i = 0; i < 8; i++) {                                              \
      uint4 u = (HSRC)[i];                                                     \
      f16x2 ux = as_h2(u.x), uy = as_h2(u.y), uz = as_h2(u.z), uw = as_h2(u.w);\
      a00 = fdot2_acc(wr[0][4*i+0], ux, a00);                                  \
      a10 = fdot2_acc(wr[1][4*i+0], ux, a10);                                  \
      a20 = fdot2_acc(wr[2][4*i+0], ux, a20);                                  \
      a01 = fdot2_acc(wr[0][4*i+1], uy, a01);                                  \
      a11 = fdot2_acc(wr[1][4*i+1], uy, a11);                                  \
      a21 = fdot2_acc(wr[2][4*i+1], uy, a21);                                  \
      a00 = fdot2_acc(wr[0][4*i+2], uz, a00);                                  \
      a10 = fdot2_acc(wr[1][4*i+2], uz, a10);                                  \
      a20 = fdot2_acc(wr[2][4*i+2], uz, a20);                                  \
      a01 = fdot2_acc(wr[0][4*i+3], uw, a01);                                  \
      a11 = fdot2_acc(wr[1][4*i+3], uw, a11);                                  \
      a21 = fdot2_acc(wr[2][4*i+3], uw, a21);                                  \
    }                                                                          \
    S0 = a00 + a01; S1 = a10 + a11; S2 = a20 + a21;                            \
  }

#define GSTEPX(CUR, NXT, IR, IZ, INN)                                          \
  {                                                                            \
    const uint4* hsrc = (const uint4*)((const char*)hb[CUR] + kh * 128);       \
    float s0, s1, s2;                                                          \
    DOT96(hsrc, s0, s1, s2);                                                   \
    const float hr = s0 + __shfl_xor(s0, 1) + bg0;                             \
    const float hz = s1 + __shfl_xor(s1, 1) + bg1;                             \
    const float hn = s2 + __shfl_xor(s2, 1) + bg2;                             \
    const float rr = 1.f / (1.f + __expf(-((IR) + hr)));                       \
    const float zz = 1.f / (1.f + __expf(-((IZ) + hz)));                       \
    const float na = (INN) + rr * hn;                                          \
    const float nn = 1.f - 2.f / (__expf(2.f * na) + 1.f);                     \
    h_own = (1.f - zz) * nn + zz * h_own;                                      \
    if (kh == 0) hb[NXT][g] = (_Float16)h_own;                                 \
    else         *y_p = h_own;                                                 \
    IR = gp_p[0]; IZ = gp_p[128]; INN = gp_p[256];                             \
    gp_p += (B_ * G3_);                                                        \
    y_p  += (B_ * H_);                                                         \
    asm volatile("s_waitcnt lgkmcnt(0)" ::: "memory");                         \
    __builtin_amdgcn_s_barrier();                                              \
    __builtin_amdgcn_sched_barrier(0x0026);                                    \
  }

__global__ __launch_bounds__(256, 1) void gru_pipe(
    float* __restrict__ gi,           // [M,384] gi0, overwritten in-place by gi1
    const float* __restrict__ w_hh0,  // [384,128]
    const float* __restrict__ b_hh0,  // [384]
    const float* __restrict__ w_ih1,  // [384,128]
    const float* __restrict__ b_ih1,  // [384]
    const float* __restrict__ w_hh1,  // [384,128]
    const float* __restrict__ b_hh1,  // [384]
    float* __restrict__ ybuf,         // [M,128] y0 then y1 (flag-ordered)
    int* __restrict__ flags)          // p0[64] | p1[64]  (in d_out)
{
    const int tid = threadIdx.x;
    const int w   = tid >> 6;        // wave 0..3
    const int l   = tid & 63;
    const int g   = w * 32 + (l >> 1);   // owned dim (pair-shared)
    const int kh  = l & 1;               // K-half
    const int role = blockIdx.x >> 6;    // 0=L0, 1=GEMM, 2=L1
    const int b    = blockIdx.x & 63;
    int* p0 = flags + b;
    int* p1 = flags + 64 + b;

    __shared__ __align__(16) _Float16 hb[2][128];   // recurrence h dbuf
    __shared__ __align__(16) f16x2 yrow[16][64];    // GEMM: 16 staged y0 rows

    if (role == 1) {
        // ------------------- GEMM stage: gi1 = b_ih1 + W_ih1 . y0 ---------
        f16x2 wr[3][32];
#pragma unroll
        for (int G = 0; G < 3; G++) {
            const float2* w2 = (const float2*)(w_ih1 + (size_t)(g + 128 * G) * 128 + kh * 64);
#pragma unroll
            for (int i = 0; i < 32; i++) {
                float2 v = w2[i];
                wr[G][i] = (f16x2){(_Float16)v.x, (_Float16)v.y};
            }
        }
        const float c0 = b_ih1[g], c1 = b_ih1[g + 128], c2 = b_ih1[g + 256];

        for (int c = 0; c < NCH_; c++) {
            if (tid == 0) wait_ge(p0, (c + 1) * CH_);
            __syncthreads();   // chunk-ready visible; protects yrow
            for (int sub = 0; sub < CH_ / 16; sub++) {
                if (sub) __syncthreads();   // protect yrow from prev subtile readers
                const int tbase = c * CH_ + sub * 16;
                for (int j = tid; j < 16 * 64; j += 256) {
                    const int s = j >> 6, p = j & 63;
                    const float2 v = ((const float2*)(ybuf +
                        ((size_t)(tbase + s) * B_ + b) * H_))[p];
                    yrow[s][p] = (f16x2){(_Float16)v.x, (_Float16)v.y};
                }
                __syncthreads();
                for (int s = 0; s < 16; s++) {
                    const uint4* hsrc = (const uint4*)yrow[s] + kh * 8;
                    float s0, s1, s2;
                    DOT96(hsrc, s0, s1, s2);
                    const float r0v = s0 + __shfl_xor(s0, 1);
                    const float r1v = s1 + __shfl_xor(s1, 1);
                    const float r2v = s2 + __shfl_xor(s2, 1);
                    if (kh == 0) {
                        float* go = gi + ((size_t)(tbase + s) * B_ + b) * G3_ + g;
                        go[0]   = r0v + c0;
                        go[128] = r1v + c1;
                        go[256] = r2v + c2;
                    }
                }
            }
            asm volatile("s_waitcnt vmcnt(0)" ::: "memory");  // gi1 stores done
            __syncthreads();
            if (tid == 0)
                __hip_atomic_store(p1, c + 1, __ATOMIC_RELEASE, __HIP_MEMORY_SCOPE_AGENT);
        }
        return;
    }

    // ------------------- recurrence (role 0 = L0, role 2 = L1) ------------
    const float* wsrc = (role == 2) ? w_hh1 : w_hh0;
    const float* bsrc = (role == 2) ? b_hh1 : b_hh0;

    f16x2 wr[3][32];
#pragma unroll
    for (int G = 0; G < 3; G++) {
        const float2* w2 = (const float2*)(wsrc + (size_t)(g + 128 * G) * 128 + kh * 64);
#pragma unroll
        for (int i = 0; i < 32; i++) {
            float2 v = w2[i];
            wr[G][i] = (f16x2){(_Float16)v.x, (_Float16)v.y};
        }
    }
    const float bg0 = bsrc[g];
    const float bg1 = bsrc[g + 128];
    const float bg2 = bsrc[g + 256];

    if (tid < 128) hb[0][tid] = (_Float16)0.f;
    float h_own = 0.f;

    const float* gi_g = gi + (size_t)b * G3_ + g;

    // L1: gate prologue prefetch (t=0,1) requires gi1 chunks 0,1 ready
    if (role == 2) {
        if (tid == 0) wait_ge(p1, 2);
        __syncthreads();
    }

    float irA = gi_g[0], izA = gi_g[128], innA = gi_g[256];
    const float* pp1 = gi_g + (size_t)(B_ * G3_);
    float irB = pp1[0], izB = pp1[128], innB = pp1[256];

    // rolling pointers: gp_p -> gi row t+2 (advanced 1 step per GSTEPX);
    // y_p -> y row t (kh==1 lanes store through it)
    const float* gp_p = gi_g + (size_t)2 * (B_ * G3_);
    float* y_p = ybuf + (size_t)b * H_ + g;

    __syncthreads();  // hb[0] init visible

    for (int c = 0; c < NCH_; c++) {
        if (role == 2) {
            const int need = (c + 2 < NCH_) ? (c + 2) : NCH_;
            if (tid == 0) wait_ge(p1, need);
            __syncthreads();
        }
        for (int i = 0; i < CH_ / 2; i++) {
            GSTEPX(0, 1, irA, izA, innA)
            GSTEPX(1, 0, irB, izB, innB)
        }
        if (role == 0) {
            asm volatile("s_waitcnt vmcnt(0)" ::: "memory");  // y0 stores done
            __syncthreads();
            if (tid == 0)
                __hip_atomic_store(p0, (c + 1) * CH_, __ATOMIC_RELEASE, __HIP_MEMORY_SCOPE_AGENT);
        }
    }
}

// ---------------------------------------------------------------------------
// K5: out[b*T+t][c] = relu(fc_b[c] + dot(fc_w[c], y[t*B+b]))
// ---------------------------------------------------------------------------
__global__ __launch_bounds__(256, 2) void fc_relu(
    const float* __restrict__ y,     // [M,128]
    const float* __restrict__ fc_w,  // [32,128]
    const float* __restrict__ fc_b,  // [32]
    float* __restrict__ out)         // [B*T,32]
{
    const int tid = threadIdx.x;
    const int c = tid & 31;
    const int slot = tid >> 5;

    float4 wr[32];
    const float4* w4 = (const float4*)(fc_w + c * 128);
#pragma unroll
    for (int i = 0; i < 32; i++) wr[i] = w4[i];
    const float bc = fc_b[c];

    __shared__ __align__(16) float rows[8][128];

    for (int grp = blockIdx.x; grp < M_ / 8; grp += gridDim.x) {
        const int m0 = grp * 8;
        __syncthreads();
        for (int i = tid; i < 8 * 128; i += 256) {
            rows[i >> 7][i & 127] = y[(long)m0 * 128 + i];
        }
        __syncthreads();
        const float4* h4 = (const float4*)rows[slot];
        float a0 = bc, a1 = 0.f, a2 = 0.f, a3 = 0.f;
#pragma unroll
        for (int i = 0; i < 32; i += 4) {
            float4 h0 = h4[i], h1 = h4[i + 1], h2 = h4[i + 2], h3 = h4[i + 3];
            a0 = fmaf(wr[i].w, h0.w, fmaf(wr[i].z, h0.z, fmaf(wr[i].y, h0.y, fmaf(wr[i].x, h0.x, a0))));
            a1 = fmaf(wr[i+1].w, h1.w, fmaf(wr[i+1].z, h1.z, fmaf(wr[i+1].y, h1.y, fmaf(wr[i+1].x, h1.x, a1))));
            a2 = fmaf(wr[i+2].w, h2.w, fmaf(wr[i+2].z, h2.z, fmaf(wr[i+2].y, h2.y, fmaf(wr[i+2].x, h2.x, a2))));
            a3 = fmaf(wr[i+3].w, h3.w, fmaf(wr[i+3].z, h3.z, fmaf(wr[i+3].y, h3.y, fmaf(wr[i+3].x, h3.x, a3))));
        }
        float acc = (a0 + a1) + (a2 + a3);
        acc = fmaxf(acc, 0.f);
        const int m = m0 + slot;
        const int t = m >> 6;
        const int b = m & 63;
        out[((long)b * T_ + t) * C_ + c] = acc;
    }
}

// ---------------------------------------------------------------------------
extern "C" void kernel_launch(void* const* d_in, const int* in_sizes, int n_in,
                              void* d_out, int out_size, void* d_ws, size_t ws_size,
                              hipStream_t stream) {
    const int*   x     = (const int*)d_in[0];
    const float* emb   = (const float*)d_in[1];
    const float* w_ih0 = (const float*)d_in[2];
    const float* w_hh0 = (const float*)d_in[3];
    const float* b_ih0 = (const float*)d_in[4];
    const float* b_hh0 = (const float*)d_in[5];
    const float* w_ih1 = (const float*)d_in[6];
    const float* w_hh1 = (const float*)d_in[7];
    const float* b_ih1 = (const float*)d_in[8];
    const float* b_hh1 = (const float*)d_in[9];
    const float* fc_w  = (const float*)d_in[10];
    const float* fc_b  = (const float*)d_in[11];
    float* out = (float*)d_out;

    // workspace: gi [M,384] fp32 (201.3 MB, gi0 overwritten in-place by gi1)
    //          + ybuf [M,128] fp32 (67.1 MB, y0 then y1) = 268.4 MB
    float* gi   = (float*)d_ws;
    float* ybuf = (float*)((char*)d_ws + (size_t)M_ * G3_ * sizeof(float));

    // pipeline flags p0|p1 at the start of d_out (overwritten by fc_relu)
    hipMemsetAsync(d_out, 0, 128 * sizeof(int), stream);

    // layer 0 input gates: MFMA GEMM
    gates_mfma<<<1536, 256, 0, stream>>>(emb, x, w_ih0, b_ih0, gi);
    // 3-stage pipelined recurrence: L0 | gi1-GEMM | L1
    gru_pipe<<<192, 256, 0, stream>>>(gi, w_hh0, b_hh0, w_ih1, b_ih1, w_hh1, b_hh1,
                                      ybuf, (int*)d_out);
    // FC + ReLU
    fc_relu<<<512, 256, 0, stream>>>(ybuf, fc_w, fc_b, out);
}